// Round 7
// baseline (251.070 us; speedup 1.0000x reference)
//
#include <hip/hip_runtime.h>
#include <math.h>

#define T_TOKENS 16384
#define D_DIM    2048
#define E_EXP    64
#define TOPK     8
#define NSL      8                   // K slices = waves per block
#define KC       32                  // k per chunk
#define NCH      (D_DIM / NSL / KC)  // 8 chunks per slice
#define TT       16                  // tokens per block (one MFMA row-tile)

typedef __attribute__((ext_vector_type(8))) short bf16x8;
typedef __attribute__((ext_vector_type(4))) float f32x4;

__device__ __forceinline__ unsigned short bf16rne(float f) {
  unsigned u = __builtin_bit_cast(unsigned, f);
  unsigned r = u + 0x7fffu + ((u >> 16) & 1u);
  return (unsigned short)(r >> 16);
}
__device__ __forceinline__ float bf16f(unsigned short h) {
  return __builtin_bit_cast(float, (unsigned)h << 16);
}

// ---------------- Kernel 0: pre-convert gate_w to frag-ordered bf16 hi/lo ----
// entry id = ((c*4 + kq)*64 + e): c = k/32 chunk, kq = k-quad, e = expert.
// Entry = 8 bf16 (16 B) = g[e][c*32 + kq*8 .. +7]. Also zeroes counts region.
__global__ __launch_bounds__(256) void convert_g_kernel(
    const float* __restrict__ gw, unsigned short* __restrict__ ph,
    unsigned short* __restrict__ pl, float* __restrict__ counts_zero)
{
  const int id = blockIdx.x * 256 + threadIdx.x;   // 0..16383
  if (blockIdx.x == 0 && threadIdx.x < E_EXP) counts_zero[threadIdx.x] = 0.0f;

  const int e  = id & 63;
  const int kq = (id >> 6) & 3;
  const int c  = id >> 8;
  const float* gp = &gw[(size_t)e * D_DIM + c * 32 + kq * 8];
  float4 v0 = *(const float4*)&gp[0];
  float4 v1 = *(const float4*)&gp[4];
  const float xs[8] = {v0.x, v0.y, v0.z, v0.w, v1.x, v1.y, v1.z, v1.w};
  bf16x8 hi, lo;
  #pragma unroll
  for (int j = 0; j < 8; ++j) {
    unsigned short h = bf16rne(xs[j]);
    hi[j] = (short)h;
    lo[j] = (short)bf16rne(xs[j] - bf16f(h));
  }
  *(bf16x8*)&ph[(size_t)id * 8] = hi;
  *(bf16x8*)&pl[(size_t)id * 8] = lo;
}

// ---------------- Kernel 1 (fused): logits + reduce + top-8 + counts ----------
// A-access-pattern fix (R5 diagnosis): every prior version read x with lanes
// spread over 16 token rows at 8 KB stride (channel-aliased gather, ~1.8 TB/s
// effective). Here each block stages its FULL 16-row x-tile (128 KB) into LDS
// with lane-CONTIGUOUS full-row reads (wave instruction = 1 KB contiguous =
// 8 consecutive lines -> full channel spread), then computes from LDS.
//   grid = T/16 = 1024 blocks, 512 thr = 8 waves = 8 K-slices (NS=8,
//   R4-validated summation order). Wave wsl: all 16 tokens, k in [wsl*256,+256).
//   A-LDS XOR-slot swizzle: row r, 16B-slot s stored at s^(r&7) (both-sides
//   involution) -> b128 reads/writes at full LDS bandwidth.
//   B: direct from L2 per chunk, depth-1 prefetch (R4/R5 proved B-path is
//   not the wall). MFMA frag formulas verbatim (global chunk = wsl*8+c).
//   Epilogue slab[8][64][16] + hist alias the A-buffer after a barrier.
__global__ __launch_bounds__(512, 2) void moe_fused_kernel(
    const float* __restrict__ x, const unsigned short* __restrict__ ph,
    const unsigned short* __restrict__ pl, const float* __restrict__ bias,
    float* __restrict__ out)
{
  __shared__ float ax[TT * D_DIM];   // 128 KB; epilogue slab+hist aliased after barrier

  const int tid  = threadIdx.x;
  const int wave = tid >> 6;
  const int lane = tid & 63;
  const int l15  = lane & 15;
  const int quad = lane >> 4;
  const int wsl  = wave;              // K slice 0..7, k0 = wsl*256
  const int tok0 = blockIdx.x * TT;

  // ---- stage full x tile: iteration i = row i; wave reads 1 KB CONTIGUOUS ----
  {
    const float* xt = &x[(size_t)tok0 * D_DIM];
    f32x4 st[16];
    #pragma unroll
    for (int i = 0; i < 16; ++i)
      st[i] = *(const f32x4*)&xt[(size_t)i * D_DIM + tid * 4];
    #pragma unroll
    for (int i = 0; i < 16; ++i) {
      const int slot = tid ^ (i & 7);          // 16B-slot swizzle, row-keyed
      *(f32x4*)&ax[i * 2048 + slot * 4] = st[i];
    }
  }

  f32x4 acc[4];
  #pragma unroll
  for (int et = 0; et < 4; ++et) acc[et] = (f32x4){0.f, 0.f, 0.f, 0.f};

  // B base: frag-packed bf16 hi/lo; global chunk index = wsl*8 + c
  const unsigned short* bh_p = &ph[(((size_t)(wsl * NCH) * 4 + quad) * 64 + l15) * 8];
  const unsigned short* bl_p = &pl[(((size_t)(wsl * NCH) * 4 + quad) * 64 + l15) * 8];

  // prologue: B(0) loads issue before the staging barrier (independent of LDS)
  bf16x8 bhc[4], blc[4];
  #pragma unroll
  for (int et = 0; et < 4; ++et) {
    bhc[et] = *(const bf16x8*)&bh_p[et * 128];
    blc[et] = *(const bf16x8*)&bl_p[et * 128];
  }

  __syncthreads();   // x tile resident

  const int sw = l15 & 7;            // read-side swizzle key (row = l15)
  #pragma unroll 1
  for (int c = 0; c < NCH; ++c) {
    // ---- depth-1 B prefetch: issue B(c+1) now, consumed next iteration ----
    bf16x8 bhn[4], bln[4];
    if (c + 1 < NCH) {
      const unsigned short* ch = bh_p + (size_t)(c + 1) * 2048;
      const unsigned short* cl = bl_p + (size_t)(c + 1) * 2048;
      #pragma unroll
      for (int et = 0; et < 4; ++et) {
        bhn[et] = *(const bf16x8*)&ch[et * 128];
        bln[et] = *(const bf16x8*)&cl[et * 128];
      }
    } else {
      #pragma unroll
      for (int et = 0; et < 4; ++et) {
        bhn[et] = bhc[et];
        bln[et] = blc[et];
      }
    }

    // ---- A-frag from LDS: row l15, slots s0, s0+1 (swizzled) ----
    const int s0 = wsl * 64 + c * 8 + quad * 2;
    f32x4 a0 = *(const f32x4*)&ax[l15 * 2048 + ((s0    ) ^ sw) * 4];
    f32x4 a1 = *(const f32x4*)&ax[l15 * 2048 + ((s0 + 1) ^ sw) * 4];

    // ---- split A to hi/lo bf16 (register-only; numerics unchanged) ----
    const float xs[8] = {a0[0], a0[1], a0[2], a0[3], a1[0], a1[1], a1[2], a1[3]};
    bf16x8 ah, al;
    #pragma unroll
    for (int j = 0; j < 8; ++j) {
      unsigned short h = bf16rne(xs[j]);
      ah[j] = (short)h;
      al[j] = (short)bf16rne(xs[j] - bf16f(h));
    }

    // ---- 12 MFMAs ----
    #pragma unroll
    for (int et = 0; et < 4; ++et) {
      acc[et] = __builtin_amdgcn_mfma_f32_16x16x32_bf16(ah, bhc[et], acc[et], 0, 0, 0);
      acc[et] = __builtin_amdgcn_mfma_f32_16x16x32_bf16(al, bhc[et], acc[et], 0, 0, 0);
      acc[et] = __builtin_amdgcn_mfma_f32_16x16x32_bf16(ah, blc[et], acc[et], 0, 0, 0);
    }

    #pragma unroll
    for (int et = 0; et < 4; ++et) { bhc[et] = bhn[et]; blc[et] = bln[et]; }
  }

  __syncthreads();   // all A-LDS reads done; safe to alias slab/hist onto ax

  // ---- epilogue: slab[slice][expert][token] + hist alias the A buffer ----
  float* slab = ax;                          // 8*64*16 floats = 32 KB
  unsigned* hist = (unsigned*)&ax[NSL * E_EXP * TT];

  // acc -> slab: D row(m)=quad*4+r (token), col(n)=et*16+l15 (expert)
  #pragma unroll
  for (int et = 0; et < 4; ++et) {
    *(f32x4*)&slab[((size_t)(wsl * E_EXP + et * 16 + l15)) * TT + quad * 4] = acc[et];
  }
  if (tid < E_EXP) hist[tid] = 0;
  __syncthreads();

  // reduce 8 slices + bias into slice 0 (order: bias, +s0..+s7 — matches the
  // R4-passing NS=8 summation). 256 threads x f32x4 = 64 experts x 16 tokens.
  if (tid < 256) {
    const int e  = tid >> 2;          // 0..63
    const int t4 = (tid & 3) * 4;     // 0,4,8,12
    const float b = bias[e];
    f32x4 v = (f32x4){b, b, b, b};
    #pragma unroll
    for (int s = 0; s < NSL; ++s) {
      f32x4 sv = *(const f32x4*)&slab[(size_t)(s * E_EXP + e) * TT + t4];
      #pragma unroll
      for (int j = 0; j < 4; ++j) v[j] += sv[j];
    }
    *(f32x4*)&slab[(size_t)e * TT + t4] = v;
  }
  __syncthreads();

  if (tid >= 64) return;   // wave 0 finishes the 16 tokens

  if (tid < TT) {
    const int t = tid;
    float l[E_EXP];
    #pragma unroll
    for (int j = 0; j < E_EXP; ++j) l[j] = slab[(size_t)j * TT + t];

    float tv[TOPK]; int tix[TOPK];
    unsigned long long used = 0ull;
    #pragma unroll
    for (int k = 0; k < TOPK; ++k) {
      float best = -INFINITY; int bi = 0;
      #pragma unroll
      for (int j = 0; j < E_EXP; ++j) {
        bool ok = (((used >> j) & 1ull) == 0ull) && (l[j] > best);  // strict >: lowest index wins ties
        best = ok ? l[j] : best;
        bi   = ok ? j : bi;
      }
      tv[k] = best; tix[k] = bi;
      used |= (1ull << bi);
    }

    float m = tv[0], s = 0.0f, w[TOPK];
    #pragma unroll
    for (int k = 0; k < TOPK; ++k) { w[k] = expf(tv[k] - m); s += w[k]; }
    float inv = 1.0f / s;

    const size_t gt = (size_t)blockIdx.x * TT + t;
    #pragma unroll
    for (int k = 0; k < TOPK; ++k) {
      out[gt * TOPK + k] = (float)tix[k];                                // indices as fp32
      out[(size_t)T_TOKENS * TOPK + gt * TOPK + k] = w[k] * inv;         // weights
    }

    #pragma unroll
    for (int k = 0; k < TOPK; ++k) atomicAdd(&hist[tix[k]], 1u);
  }
  __threadfence_block();   // order wave-0's LDS atomics before its reads
  atomicAdd(&out[2 * (size_t)T_TOKENS * TOPK + tid], (float)hist[tid]);
}

extern "C" void kernel_launch(void* const* d_in, const int* in_sizes, int n_in,
                              void* d_out, int out_size, void* d_ws, size_t ws_size,
                              hipStream_t stream) {
  const float* x    = (const float*)d_in[0];
  const float* gw   = (const float*)d_in[1];
  const float* bias = (const float*)d_in[2];
  float* out  = (float*)d_out;

  // ws layout: ph (256 KB) | pl (256 KB)
  unsigned short* ph = (unsigned short*)d_ws;
  unsigned short* pl = ph + (size_t)E_EXP * D_DIM;

  convert_g_kernel<<<dim3(E_EXP * D_DIM / 8 / 256), dim3(256), 0, stream>>>(
      gw, ph, pl, out + 2 * (size_t)T_TOKENS * TOPK);
  moe_fused_kernel<<<dim3(T_TOKENS / TT), dim3(512), 0, stream>>>(
      x, ph, pl, bias, out);
}

// Round 8
// 214.066 us; speedup vs baseline: 1.1729x; 1.1729x over previous
//
#include <hip/hip_runtime.h>
#include <math.h>

#define T_TOKENS 16384
#define D_DIM    2048
#define E_EXP    64
#define TOPK     8
#define NS       4                   // K slices (across waves within a block)
#define KC       32                  // k per chunk (phase)
#define NCH      (D_DIM / NS / KC)   // 16 phases
#define TT       32                  // tokens per block (2 blocks/CU)
#define TOKP     36                  // token stride in epilogue slab (16B-aligned rows)

typedef __attribute__((ext_vector_type(8))) short bf16x8;
typedef __attribute__((ext_vector_type(4))) float f32x4;

__device__ __forceinline__ unsigned short bf16rne(float f) {
  unsigned u = __builtin_bit_cast(unsigned, f);
  unsigned r = u + 0x7fffu + ((u >> 16) & 1u);
  return (unsigned short)(r >> 16);
}
__device__ __forceinline__ float bf16f(unsigned short h) {
  return __builtin_bit_cast(float, (unsigned)h << 16);
}

// async global->LDS, 16 B per lane. LDS dest must be WAVE-UNIFORM (lane*16
// implicit); global src is per-lane (m97 pattern).
__device__ __forceinline__ void gload16(const void* g, void* l) {
  __builtin_amdgcn_global_load_lds(
      (const __attribute__((address_space(1))) unsigned int*)g,
      (__attribute__((address_space(3))) unsigned int*)l,
      16, 0, 0);
}

// ---------------- Kernel 0: pre-convert gate_w to frag-ordered bf16 hi/lo ----
// entry id = ((c*4 + kq)*64 + e): c = k/32 chunk, kq = k-quad, e = expert.
// Entry = 8 bf16 (16 B) = g[e][c*32 + kq*8 .. +7]. Also zeroes counts region.
__global__ __launch_bounds__(256) void convert_g_kernel(
    const float* __restrict__ gw, unsigned short* __restrict__ ph,
    unsigned short* __restrict__ pl, float* __restrict__ counts_zero)
{
  const int id = blockIdx.x * 256 + threadIdx.x;   // 0..16383
  if (blockIdx.x == 0 && threadIdx.x < E_EXP) counts_zero[threadIdx.x] = 0.0f;

  const int e  = id & 63;
  const int kq = (id >> 6) & 3;
  const int c  = id >> 8;
  const float* gp = &gw[(size_t)e * D_DIM + c * 32 + kq * 8];
  float4 v0 = *(const float4*)&gp[0];
  float4 v1 = *(const float4*)&gp[4];
  const float xs[8] = {v0.x, v0.y, v0.z, v0.w, v1.x, v1.y, v1.z, v1.w};
  bf16x8 hi, lo;
  #pragma unroll
  for (int j = 0; j < 8; ++j) {
    unsigned short h = bf16rne(xs[j]);
    hi[j] = (short)h;
    lo[j] = (short)bf16rne(xs[j] - bf16f(h));
  }
  *(bf16x8*)&ph[(size_t)id * 8] = hi;
  *(bf16x8*)&pl[(size_t)id * 8] = lo;
}

// ---------------- Kernel 1 (fused): logits + reduce + top-8 + counts ----------
// R5 geometry/numerics/epilogue verbatim (TT=32, 512 thr = 2 token-groups x 4
// K-slices, 2 blocks/CU). NEW: all staging via bulk global_load_lds (m97
// pattern) to fix the MLP starvation diagnosed over R3-R7 (all pipes idle,
// ~76 us regardless of design; exposed HBM miss latency with depth-1/2
// register prefetch). Per phase the block issues 48 KB of async loads (16 KB
// A + 32 KB B, 6 insts/wave) with no dependent consumer until the barrier:
//   sync; STAGE(c+1); sync; compute(c)  -- single buffer, 2 barriers (m97).
// A: LDS [sl][32 tok][32 k] f32, lane-linear dest; XOR-slot involution
//   (slot ^= tok&7) applied on the GLOBAL source (rule #21) and on reads ->
//   2-way banks (free). B: LDS layout byte-identical to R5's staged layout
//   (sl*4096 + hl*2048 + kq*512 + e*8 shorts), read formulas unchanged.
__global__ __launch_bounds__(512, 4) void moe_fused_kernel(
    const float* __restrict__ x, const unsigned short* __restrict__ ph,
    const unsigned short* __restrict__ pl, const float* __restrict__ bias,
    float* __restrict__ out)
{
  __shared__ char smem[49152];    // 16 KB A + 32 KB B; epilogue slab alias
  __shared__ unsigned hist[E_EXP];

  const int tid  = threadIdx.x;
  const int wave = tid >> 6;
  const int lane = tid & 63;
  const int l15  = lane & 15;
  const int quad = lane >> 4;
  const int wg   = wave & 1;          // token group (0..1)
  const int wsl  = wave >> 1;         // K slice (0..3)
  const int tok0 = blockIdx.x * TT;
  const int tokw = tok0 + wg * 16;

  // ---- staging descriptors ----
  // A inst j = wave*2 + i (j=0..15): covers slice j>>2, tokens (j&3)*8..+7.
  // lane l -> tok_local = l>>3, phys_slot = l&7; global logical slot =
  // (l&7) ^ (tok&7)  (tok&7 == (l>>3)&7 since (j&3)*8 % 8 == 0).
  const int jA0 = wave * 2;
  const int jA1 = wave * 2 + 1;
  const int aslot = ((lane & 7) ^ ((lane >> 3) & 7)) * 4;   // floats
  const float* gA0 = &x[(size_t)(tok0 + (jA0 & 3) * 8 + (lane >> 3)) * D_DIM
                        + (jA0 >> 2) * (D_DIM / NS) + aslot];
  const float* gA1 = &x[(size_t)(tok0 + (jA1 & 3) * 8 + (lane >> 3)) * D_DIM
                        + (jA1 >> 2) * (D_DIM / NS) + aslot];
  // B inst m = wave*4 + i (m=0..31): sl = m>>3, hl = (m>>2)&1, seg(kq) = m&3.
  // lane l = expert e. LDS byte = 16384 + m*1024 (matches read layout).
  const int mB = wave * 4;
  const unsigned short* gB[4];
  #pragma unroll
  for (int i = 0; i < 4; ++i) {
    const int m = mB + i;
    const unsigned short* base = ((m >> 2) & 1) ? pl : ph;
    gB[i] = base + ((size_t)((m >> 3) * NCH)) * 2048 + (m & 3) * 512 + lane * 8;
  }

#define STAGE(c)                                                           \
  {                                                                        \
    gload16(gA0 + (size_t)(c) * KC, (void*)(smem + jA0 * 1024));           \
    gload16(gA1 + (size_t)(c) * KC, (void*)(smem + jA1 * 1024));           \
    gload16(gB[0] + (size_t)(c) * 2048, (void*)(smem + 16384 + (mB+0)*1024)); \
    gload16(gB[1] + (size_t)(c) * 2048, (void*)(smem + 16384 + (mB+1)*1024)); \
    gload16(gB[2] + (size_t)(c) * 2048, (void*)(smem + 16384 + (mB+2)*1024)); \
    gload16(gB[3] + (size_t)(c) * 2048, (void*)(smem + 16384 + (mB+3)*1024)); \
  }

  f32x4 acc[4];
  #pragma unroll
  for (int et = 0; et < 4; ++et) acc[et] = (f32x4){0.f, 0.f, 0.f, 0.f};

  // read-side bases (c-independent; single buffer)
  const float* aRow = (const float*)smem + ((wsl * 32 + wg * 16 + l15) * 32);
  const int ps0 = ((quad * 2)     ^ (l15 & 7)) * 4;   // floats
  const int ps1 = ((quad * 2 + 1) ^ (l15 & 7)) * 4;
  const unsigned short* bq = (const unsigned short*)(smem + 16384)
                             + wsl * 4096 + quad * 512 + l15 * 8;

  STAGE(0);
  __syncthreads();   // phase 0 resident

  #pragma unroll 1
  for (int c = 0; c < NCH; ++c) {
    // ---- A-frag from LDS (swizzled slots; logical k = quad*8..+7) ----
    f32x4 a0 = *(const f32x4*)&aRow[ps0];
    f32x4 a1 = *(const f32x4*)&aRow[ps1];

    // ---- B-frags from LDS (layout identical to R5) ----
    bf16x8 bh[4], bl[4];
    #pragma unroll
    for (int et = 0; et < 4; ++et) {
      bh[et] = *(const bf16x8*)&bq[et * 128];
      bl[et] = *(const bf16x8*)&bq[2048 + et * 128];
    }

    // ---- split A to hi/lo bf16 (register-only; numerics unchanged) ----
    const float xs[8] = {a0[0], a0[1], a0[2], a0[3], a1[0], a1[1], a1[2], a1[3]};
    bf16x8 ah, al;
    #pragma unroll
    for (int j = 0; j < 8; ++j) {
      unsigned short h = bf16rne(xs[j]);
      ah[j] = (short)h;
      al[j] = (short)bf16rne(xs[j] - bf16f(h));
    }

    // ---- 12 MFMAs ----
    #pragma unroll
    for (int et = 0; et < 4; ++et) {
      acc[et] = __builtin_amdgcn_mfma_f32_16x16x32_bf16(ah, bh[et], acc[et], 0, 0, 0);
      acc[et] = __builtin_amdgcn_mfma_f32_16x16x32_bf16(al, bh[et], acc[et], 0, 0, 0);
      acc[et] = __builtin_amdgcn_mfma_f32_16x16x32_bf16(ah, bl[et], acc[et], 0, 0, 0);
    }

    __syncthreads();   // all reads of the buffer done
    if (c + 1 < NCH) {
      STAGE(c + 1);
      __syncthreads(); // phase c+1 resident
    }
  }

  // ---- epilogue (R5 verbatim; slab aliases the staging buffer) ----
  float* slab = (float*)smem;                // NS*E_EXP*TOKP floats = 36864 B

  // acc -> slab: D row(m)=quad*4+r (token), col(n)=et*16+l15 (expert)
  #pragma unroll
  for (int et = 0; et < 4; ++et) {
    *(f32x4*)&slab[((size_t)(wsl * E_EXP + et * 16 + l15)) * TOKP + wg * 16 + quad * 4] = acc[et];
  }
  if (tid < E_EXP) hist[tid] = 0;
  __syncthreads();

  // reduce 4 slices + bias into slice 0 (512 thr x f32x4 = 64 experts x 32 tokens).
  // Summation order identical to previous passing versions: bias, +s0..+s3.
  {
    const int e  = tid >> 3;          // 0..63
    const int t4 = (tid & 7) * 4;     // 0..28
    f32x4 s0 = *(const f32x4*)&slab[(size_t)(0 * E_EXP + e) * TOKP + t4];
    f32x4 s1 = *(const f32x4*)&slab[(size_t)(1 * E_EXP + e) * TOKP + t4];
    f32x4 s2 = *(const f32x4*)&slab[(size_t)(2 * E_EXP + e) * TOKP + t4];
    f32x4 s3 = *(const f32x4*)&slab[(size_t)(3 * E_EXP + e) * TOKP + t4];
    const float b = bias[e];
    f32x4 v;
    #pragma unroll
    for (int j = 0; j < 4; ++j) v[j] = (((b + s0[j]) + s1[j]) + s2[j]) + s3[j];
    *(f32x4*)&slab[(size_t)(0 * E_EXP + e) * TOKP + t4] = v;
  }
  __syncthreads();

  if (tid >= 64) return;   // waves 1..7 done; wave 0 finishes the 32 tokens

  if (tid < TT) {
    const int t = tid;
    float l[E_EXP];
    #pragma unroll
    for (int j = 0; j < E_EXP; ++j) l[j] = slab[(size_t)j * TOKP + t];

    float tv[TOPK]; int tix[TOPK];
    unsigned long long used = 0ull;
    #pragma unroll
    for (int k = 0; k < TOPK; ++k) {
      float best = -INFINITY; int bi = 0;
      #pragma unroll
      for (int j = 0; j < E_EXP; ++j) {
        bool ok = (((used >> j) & 1ull) == 0ull) && (l[j] > best);  // strict >: lowest index wins ties
        best = ok ? l[j] : best;
        bi   = ok ? j : bi;
      }
      tv[k] = best; tix[k] = bi;
      used |= (1ull << bi);
    }

    float m = tv[0], s = 0.0f, w[TOPK];
    #pragma unroll
    for (int k = 0; k < TOPK; ++k) { w[k] = expf(tv[k] - m); s += w[k]; }
    float inv = 1.0f / s;

    const size_t gt = (size_t)blockIdx.x * TT + t;
    #pragma unroll
    for (int k = 0; k < TOPK; ++k) {
      out[gt * TOPK + k] = (float)tix[k];                                // indices as fp32
      out[(size_t)T_TOKENS * TOPK + gt * TOPK + k] = w[k] * inv;         // weights
    }

    #pragma unroll
    for (int k = 0; k < TOPK; ++k) atomicAdd(&hist[tix[k]], 1u);
  }
  __threadfence_block();   // order wave-0's LDS atomics before its reads
  atomicAdd(&out[2 * (size_t)T_TOKENS * TOPK + tid], (float)hist[tid]);
}

extern "C" void kernel_launch(void* const* d_in, const int* in_sizes, int n_in,
                              void* d_out, int out_size, void* d_ws, size_t ws_size,
                              hipStream_t stream) {
  const float* x    = (const float*)d_in[0];
  const float* gw   = (const float*)d_in[1];
  const float* bias = (const float*)d_in[2];
  float* out  = (float*)d_out;

  // ws layout: ph (256 KB) | pl (256 KB)
  unsigned short* ph = (unsigned short*)d_ws;
  unsigned short* pl = ph + (size_t)E_EXP * D_DIM;

  convert_g_kernel<<<dim3(E_EXP * D_DIM / 8 / 256), dim3(256), 0, stream>>>(
      gw, ph, pl, out + 2 * (size_t)T_TOKENS * TOPK);
  moe_fused_kernel<<<dim3(T_TOKENS / TT), dim3(512), 0, stream>>>(
      x, ph, pl, bias, out);
}

// Round 9
// 212.925 us; speedup vs baseline: 1.1791x; 1.0054x over previous
//
#include <hip/hip_runtime.h>
#include <math.h>

#define T_TOKENS 16384
#define D_DIM    2048
#define E_EXP    64
#define TOPK     8
#define NS       4                   // K slices (across waves; interleaved per phase)
#define PH       8                   // K phases
#define PKC      256                 // k per phase (1 KB per token row)
#define TT       32                  // tokens per block (2 blocks/CU)
#define TOKP     36                  // token stride in epilogue slab (16B-aligned rows)

typedef __attribute__((ext_vector_type(8))) short bf16x8;
typedef __attribute__((ext_vector_type(4))) float f32x4;

__device__ __forceinline__ unsigned short bf16rne(float f) {
  unsigned u = __builtin_bit_cast(unsigned, f);
  unsigned r = u + 0x7fffu + ((u >> 16) & 1u);
  return (unsigned short)(r >> 16);
}
__device__ __forceinline__ float bf16f(unsigned short h) {
  return __builtin_bit_cast(float, (unsigned)h << 16);
}

// async global->LDS, 16 B per lane; LDS dest wave-uniform base + lane*16.
__device__ __forceinline__ void gload16(const void* g, void* l) {
  __builtin_amdgcn_global_load_lds(
      (const __attribute__((address_space(1))) unsigned int*)g,
      (__attribute__((address_space(3))) unsigned int*)l,
      16, 0, 0);
}

// ---------------- Kernel 0: pre-convert gate_w to frag-ordered bf16 hi/lo ----
// entry id = ((c*4 + kq)*64 + e): c = k/32 chunk, kq = k-quad, e = expert.
// Entry = 8 bf16 (16 B) = g[e][c*32 + kq*8 .. +7]. Also zeroes counts region.
__global__ __launch_bounds__(256) void convert_g_kernel(
    const float* __restrict__ gw, unsigned short* __restrict__ ph,
    unsigned short* __restrict__ pl, float* __restrict__ counts_zero)
{
  const int id = blockIdx.x * 256 + threadIdx.x;   // 0..16383
  if (blockIdx.x == 0 && threadIdx.x < E_EXP) counts_zero[threadIdx.x] = 0.0f;

  const int e  = id & 63;
  const int kq = (id >> 6) & 3;
  const int c  = id >> 8;
  const float* gp = &gw[(size_t)e * D_DIM + c * 32 + kq * 8];
  float4 v0 = *(const float4*)&gp[0];
  float4 v1 = *(const float4*)&gp[4];
  const float xs[8] = {v0.x, v0.y, v0.z, v0.w, v1.x, v1.y, v1.z, v1.w};
  bf16x8 hi, lo;
  #pragma unroll
  for (int j = 0; j < 8; ++j) {
    unsigned short h = bf16rne(xs[j]);
    hi[j] = (short)h;
    lo[j] = (short)bf16rne(xs[j] - bf16f(h));
  }
  *(bf16x8*)&ph[(size_t)id * 8] = hi;
  *(bf16x8*)&pl[(size_t)id * 8] = lo;
}

// ---------------- Kernel 1 (fused): logits + reduce + top-8 + counts ----------
// R5 geometry/epilogue verbatim (512 blocks x 512 thr = 2 tg x 4 ksl, 2/CU).
// NEW (the never-run experiment): every x staging instruction is CONTIGUOUS —
// one gload16 = 64 lanes x 16 B = one token's 1 KB row segment (the fill-
// kernel pattern that hits 7 TB/s). Phase = 256 k; A dbuf 2 x 32 KB.
// K-slices interleave: wave (wg,wsl) accumulates k in {p*256+wsl*64..+64} for
// all p — valid 4-way split-K, reduce unchanged (fp32 accum; order change ok).
// Bank fix: 16B-slot XOR by row&7, applied as a UNIFORM lane-permute of the
// global src (row const per instruction -> same 1 KB span, same transactions;
// rule-21 involution) and re-applied on the LDS read side.
// VMEM order per phase: B loads (L2-hot) FIRST, then STAGE(p+1) -> MFMA's
// counted vmcnt wait for B leaves the A stage in flight; barrier drains it
// only after it had the whole phase to complete.
__global__ __launch_bounds__(512, 4) void moe_fused_kernel(
    const float* __restrict__ x, const unsigned short* __restrict__ ph,
    const unsigned short* __restrict__ pl, const float* __restrict__ bias,
    float* __restrict__ out)
{
  __shared__ char smem[65536];    // A dbuf 2 x 32 KB; epilogue slab alias
  __shared__ unsigned hist[E_EXP];

  const int tid  = threadIdx.x;
  const int wave = tid >> 6;
  const int lane = tid & 63;
  const int l15  = lane & 15;
  const int quad = lane >> 4;
  const int wg   = wave & 1;          // token group (0..1)
  const int wsl  = wave >> 1;         // K slice (0..3)
  const int tok0 = blockIdx.x * TT;

  // ---- staging: wave stages rows wave*4 .. wave*4+3; 1 instruction = 1 row ----
  const int srow = wave * 4;
  const float* gS[4];
  #pragma unroll
  for (int i = 0; i < 4; ++i) {
    const int row = srow + i;
    // uniform lane-permute of 16B units within the row (key = row&7)
    gS[i] = &x[(size_t)(tok0 + row) * D_DIM + (size_t)(lane ^ (row & 7)) * 4];
  }

#define STAGE(p, buf)                                                      \
  {                                                                        \
    gload16(gS[0] + (size_t)(p) * PKC, (void*)(smem + (buf) * 32768 + (srow + 0) * 1024)); \
    gload16(gS[1] + (size_t)(p) * PKC, (void*)(smem + (buf) * 32768 + (srow + 1) * 1024)); \
    gload16(gS[2] + (size_t)(p) * PKC, (void*)(smem + (buf) * 32768 + (srow + 2) * 1024)); \
    gload16(gS[3] + (size_t)(p) * PKC, (void*)(smem + (buf) * 32768 + (srow + 3) * 1024)); \
  }

  // B frag bases (frag-packed bf16 hi/lo; chunk cg stride 2048 shorts)
  const unsigned short* bh0 = ph + quad * 512 + l15 * 8;
  const unsigned short* bl0 = pl + quad * 512 + l15 * 8;

  f32x4 acc[4];
  #pragma unroll
  for (int et = 0; et < 4; ++et) acc[et] = (f32x4){0.f, 0.f, 0.f, 0.f};

  const int swk = l15 & 7;            // read-side swizzle key (row&7 = l15&7)

  STAGE(0, 0);
  __syncthreads();   // phase 0 resident

  int buf = 0;
  #pragma unroll 1
  for (int p = 0; p < PH; ++p) {
    // ---- B for both 32-k sub-chunks (issue BEFORE the stage) ----
    bf16x8 bh[2][4], bl[2][4];
    #pragma unroll
    for (int sub = 0; sub < 2; ++sub) {
      const size_t cg = (size_t)(p * 8 + wsl * 2 + sub) * 2048;
      #pragma unroll
      for (int et = 0; et < 4; ++et) {
        bh[sub][et] = *(const bf16x8*)&bh0[cg + et * 128];
        bl[sub][et] = *(const bf16x8*)&bl0[cg + et * 128];
      }
    }

    // ---- issue next phase's A stage (in flight across the whole phase) ----
    if (p + 1 < PH) STAGE(p + 1, buf ^ 1);

    const float* ab = (const float*)(smem + buf * 32768) + (wg * 16 + l15) * 256;

    #pragma unroll
    for (int sub = 0; sub < 2; ++sub) {
      // ---- A-frag from LDS: row wg*16+l15, logical slots s0,s0+1 (swizzled) ----
      const int s0 = wsl * 16 + sub * 8 + quad * 2;
      f32x4 a0 = *(const f32x4*)&ab[((s0    ) ^ swk) * 4];
      f32x4 a1 = *(const f32x4*)&ab[((s0 + 1) ^ swk) * 4];

      // ---- split A to hi/lo bf16 (register-only; numerics unchanged) ----
      const float xs[8] = {a0[0], a0[1], a0[2], a0[3], a1[0], a1[1], a1[2], a1[3]};
      bf16x8 ah, al;
      #pragma unroll
      for (int j = 0; j < 8; ++j) {
        unsigned short h = bf16rne(xs[j]);
        ah[j] = (short)h;
        al[j] = (short)bf16rne(xs[j] - bf16f(h));
      }

      // ---- 12 MFMAs ----
      #pragma unroll
      for (int et = 0; et < 4; ++et) {
        acc[et] = __builtin_amdgcn_mfma_f32_16x16x32_bf16(ah, bh[sub][et], acc[et], 0, 0, 0);
        acc[et] = __builtin_amdgcn_mfma_f32_16x16x32_bf16(al, bh[sub][et], acc[et], 0, 0, 0);
        acc[et] = __builtin_amdgcn_mfma_f32_16x16x32_bf16(ah, bl[sub][et], acc[et], 0, 0, 0);
      }
    }

    __syncthreads();   // drains the (already-progressed) stage; swap buffers
    buf ^= 1;
  }

  // ---- epilogue (R5 verbatim; slab aliases the staging buffers) ----
  float* slab = (float*)smem;                // NS*E_EXP*TOKP floats = 36864 B

  // acc -> slab: D row(m)=quad*4+r (token), col(n)=et*16+l15 (expert)
  #pragma unroll
  for (int et = 0; et < 4; ++et) {
    *(f32x4*)&slab[((size_t)(wsl * E_EXP + et * 16 + l15)) * TOKP + wg * 16 + quad * 4] = acc[et];
  }
  if (tid < E_EXP) hist[tid] = 0;
  __syncthreads();

  // reduce 4 slices + bias into slice 0 (512 thr x f32x4 = 64 experts x 32 tokens).
  // Summation order: bias, +s0..+s3 (matches prior passing versions).
  {
    const int e  = tid >> 3;          // 0..63
    const int t4 = (tid & 7) * 4;     // 0..28
    f32x4 s0 = *(const f32x4*)&slab[(size_t)(0 * E_EXP + e) * TOKP + t4];
    f32x4 s1 = *(const f32x4*)&slab[(size_t)(1 * E_EXP + e) * TOKP + t4];
    f32x4 s2 = *(const f32x4*)&slab[(size_t)(2 * E_EXP + e) * TOKP + t4];
    f32x4 s3 = *(const f32x4*)&slab[(size_t)(3 * E_EXP + e) * TOKP + t4];
    const float b = bias[e];
    f32x4 v;
    #pragma unroll
    for (int j = 0; j < 4; ++j) v[j] = (((b + s0[j]) + s1[j]) + s2[j]) + s3[j];
    *(f32x4*)&slab[(size_t)(0 * E_EXP + e) * TOKP + t4] = v;
  }
  __syncthreads();

  if (tid >= 64) return;   // waves 1..7 done; wave 0 finishes the 32 tokens

  if (tid < TT) {
    const int t = tid;
    float l[E_EXP];
    #pragma unroll
    for (int j = 0; j < E_EXP; ++j) l[j] = slab[(size_t)j * TOKP + t];

    float tv[TOPK]; int tix[TOPK];
    unsigned long long used = 0ull;
    #pragma unroll
    for (int k = 0; k < TOPK; ++k) {
      float best = -INFINITY; int bi = 0;
      #pragma unroll
      for (int j = 0; j < E_EXP; ++j) {
        bool ok = (((used >> j) & 1ull) == 0ull) && (l[j] > best);  // strict >: lowest index wins ties
        best = ok ? l[j] : best;
        bi   = ok ? j : bi;
      }
      tv[k] = best; tix[k] = bi;
      used |= (1ull << bi);
    }

    float m = tv[0], s = 0.0f, w[TOPK];
    #pragma unroll
    for (int k = 0; k < TOPK; ++k) { w[k] = expf(tv[k] - m); s += w[k]; }
    float inv = 1.0f / s;

    const size_t gt = (size_t)blockIdx.x * TT + t;
    #pragma unroll
    for (int k = 0; k < TOPK; ++k) {
      out[gt * TOPK + k] = (float)tix[k];                                // indices as fp32
      out[(size_t)T_TOKENS * TOPK + gt * TOPK + k] = w[k] * inv;         // weights
    }

    #pragma unroll
    for (int k = 0; k < TOPK; ++k) atomicAdd(&hist[tix[k]], 1u);
  }
  __threadfence_block();   // order wave-0's LDS atomics before its reads
  atomicAdd(&out[2 * (size_t)T_TOKENS * TOPK + tid], (float)hist[tid]);
}

extern "C" void kernel_launch(void* const* d_in, const int* in_sizes, int n_in,
                              void* d_out, int out_size, void* d_ws, size_t ws_size,
                              hipStream_t stream) {
  const float* x    = (const float*)d_in[0];
  const float* gw   = (const float*)d_in[1];
  const float* bias = (const float*)d_in[2];
  float* out  = (float*)d_out;

  // ws layout: ph (256 KB) | pl (256 KB)
  unsigned short* ph = (unsigned short*)d_ws;
  unsigned short* pl = ph + (size_t)E_EXP * D_DIM;

  convert_g_kernel<<<dim3(E_EXP * D_DIM / 8 / 256), dim3(256), 0, stream>>>(
      gw, ph, pl, out + 2 * (size_t)T_TOKENS * TOPK);
  moe_fused_kernel<<<dim3(T_TOKENS / TT), dim3(512), 0, stream>>>(
      x, ph, pl, bias, out);
}